// Round 7
// baseline (47.378 us; speedup 1.0000x reference)
//
#include <hip/hip_runtime.h>

#define BATCH 262144
#define M 64
#define NROW 32              // rows per 256-thread block (8 rows per wave)
#define ROWDW 129            // dwords per row
#define NDW (NROW * ROWDW)   // 4128 dwords per block region
#define NT 256
#define W4N 258              // float4 per wave segment (8 rows * 129 dw / 4)

constexpr float KDT  = 1.0f / 48000.0f;
constexpr float EPSF = 1e-12f;

typedef float f4 __attribute__((ext_vector_type(4)));

// DPP rotation-add within a 16-lane row group: after ror 1,2,4,8 every lane
// holds the full 16-lane sum. Pure VALU, no LDS pipe.
template <int CTRL>
__device__ __forceinline__ float dpp_ror_add(float x) {
    int xi = __builtin_bit_cast(int, x);
    int r  = __builtin_amdgcn_update_dpp(0, xi, CTRL, 0xF, 0xF, true);
    return x + __builtin_bit_cast(float, r);
}
__device__ __forceinline__ float rsum16(float x) {
    x = dpp_ror_add<0x121>(x);  // row_ror:1
    x = dpp_ror_add<0x122>(x);  // row_ror:2
    x = dpp_ror_add<0x124>(x);  // row_ror:4
    x = dpp_ror_add<0x128>(x);  // row_ror:8
    return x;
}

// Fully wave-local: wave w owns rows 8w..8w+7 of the block region, stages them
// through its private LDS segment, computes, and stores them back. No block
// barriers anywhere — LDS ordering within a wave is guaranteed by lgkmcnt.
__global__ __launch_bounds__(NT) void sav_kernel(
    const float* __restrict__ y0,
    const float* __restrict__ dp,
    const float* __restrict__ dm,
    const float* __restrict__ omega_sq,
    const float* __restrict__ mu_p,
    const float* __restrict__ Phi_e,
    const float* __restrict__ fe_points,
    const int*   __restrict__ n_p,
    float* __restrict__ out)
{
    __shared__ float lds[NDW];   // 16512 B; 129 % 32 == 1 keeps scalar reads 2-way (free)
    f4* lds4 = (f4*)lds;

    const int tid  = threadIdx.x;
    const int lane = tid & 63;
    const int w    = tid >> 6;           // wave in block
    const int W4   = W4N * w;            // wave's f4 base (global and LDS)

    // ---------- load: wave-private sweep, all loads issued first ----------
    const f4* gin = (const f4*)(y0 + (size_t)blockIdx.x * NDW);
    const f4 v0 = gin[W4 + lane];
    const f4 v1 = gin[W4 + 64 + lane];
    const f4 v2 = gin[W4 + 128 + lane];
    const f4 v3 = gin[W4 + 192 + lane];
    f4 vt = {};
    if (lane < 2) vt = gin[W4 + 256 + lane];

    const int sl = lane & 15;            // sub-lane within 16-lane row group
    const int g  = lane >> 4;            // group within wave (0..3)

    const int   n  = *n_p;
    const float mu = *mu_p;

    const f4 dpv = ((const f4*)dp)[sl];
    const f4 dmv = ((const f4*)dm)[sl];
    const f4 osq = ((const f4*)omega_sq)[sl];
    const f4 phe = ((const f4*)Phi_e)[sl];

    const int bA = blockIdx.x * NROW + 8 * w + g;   // row for pass 0
    const float feA = fe_points[(size_t)bA * 16 + n];
    const float feB = fe_points[(size_t)(bA + 4) * 16 + n];

    lds4[W4 + lane]       = v0;
    lds4[W4 + 64 + lane]  = v1;
    lds4[W4 + 128 + lane] = v2;
    lds4[W4 + 192 + lane] = v3;
    if (lane < 2) lds4[W4 + 256 + lane] = vt;

    // ---------- compute: 2 rows per group, wave-local (no barrier) ----------
    const float c   = 0.5f * KDT * mu;
    const float mu2 = mu * mu;
    float idp[4];
    #pragma unroll
    for (int j = 0; j < 4; ++j) idp[j] = __builtin_amdgcn_rcpf(dpv[j]);

    #pragma unroll 1
    for (int rr = 0; rr < 2; ++rr) {
        const int r = 8 * w + g + 4 * rr;    // rows 8w..8w+7 across both passes
        const float fe = rr ? feB : feA;
        float* lrow = &lds[r * ROWDW];

        float q0v[4], p0v[4];
        #pragma unroll
        for (int j = 0; j < 4; ++j) {
            q0v[j] = lrow[4 * sl + j];
            p0v[j] = lrow[M + 4 * sl + j];
        }
        const float psi0 = lrow[2 * M];

        float qh[4], q3[4];
        float lq4 = 0.0f;
        #pragma unroll
        for (int j = 0; j < 4; ++j) {
            const float q  = q0v[j] + 0.5f * KDT * p0v[j];
            const float q2 = q * q;
            qh[j] = q;
            q3[j] = q2 * q;
            lq4  += q2 * q2;
        }

        const float s = rsum16(lq4);                      // sum(qh^4)
        const float inv_psi = __builtin_amdgcn_rsqf(0.5f * s + EPSF);

        float g0[4], b0[4];
        float ls1 = 0.0f, ls3 = 0.0f;
        #pragma unroll
        for (int j = 0; j < 4; ++j) {
            g0[j] = -q3[j] * inv_psi;
            const float a0 = c * g0[j];
            b0[j] = a0 * idp[j];
            ls1 += a0 * p0v[j];
            ls3 += a0 * b0[j];
        }

        const float s1 = rsum16(ls1);                     // sum(a0*p0)
        const float s3 = rsum16(ls3);                     // sum(a0*b0)

        // p1 pre-division (reference uses THIS value inside sum(b0*p1))
        const float mu2psi = mu2 * psi0;
        float p1p[4];
        float ls2 = 0.0f;
        #pragma unroll
        for (int j = 0; j < 4; ++j) {
            p1p[j] = dmv[j] * p0v[j] - (c * g0[j]) * s1
                   + KDT * (-osq[j] * qh[j] - mu2psi * g0[j] + phe[j] * fe);
            ls2 += b0[j] * p1p[j];
        }

        const float s2 = rsum16(ls2);                     // sum(b0*p1_pre)
        const float t  = s2 * __builtin_amdgcn_rcpf(1.0f + s3);

        float p1[4];
        float lsg = 0.0f;
        #pragma unroll
        for (int j = 0; j < 4; ++j) {
            p1[j] = p1p[j] * idp[j] - b0[j] * t;
            lsg  += g0[j] * (0.5f * (p0v[j] + p1[j]));
        }

        const float sg   = rsum16(lsg);                   // sum(g0*p_half)
        const float psi1 = psi0 + KDT * sg;

        // write back to the same (wave-private) LDS cells
        #pragma unroll
        for (int j = 0; j < 4; ++j) {
            lrow[4 * sl + j]     = qh[j] + 0.5f * KDT * p1[j];  // q1
            lrow[M + 4 * sl + j] = p1[j];
        }
        if (sl == 0) lrow[2 * M] = psi1;
    }

    // ---------- store: wave-private sweep, nontemporal (no barrier) ----------
    f4* gout = (f4*)(out + (size_t)blockIdx.x * NDW);
    __builtin_nontemporal_store(lds4[W4 + lane],       &gout[W4 + lane]);
    __builtin_nontemporal_store(lds4[W4 + 64 + lane],  &gout[W4 + 64 + lane]);
    __builtin_nontemporal_store(lds4[W4 + 128 + lane], &gout[W4 + 128 + lane]);
    __builtin_nontemporal_store(lds4[W4 + 192 + lane], &gout[W4 + 192 + lane]);
    if (lane < 2)
        __builtin_nontemporal_store(lds4[W4 + 256 + lane], &gout[W4 + 256 + lane]);
}

extern "C" void kernel_launch(void* const* d_in, const int* in_sizes, int n_in,
                              void* d_out, int out_size, void* d_ws, size_t ws_size,
                              hipStream_t stream) {
    const float* y0        = (const float*)d_in[0];
    const float* dp        = (const float*)d_in[1];
    const float* dm        = (const float*)d_in[2];
    const float* omega_sq  = (const float*)d_in[3];
    const float* mu        = (const float*)d_in[4];
    const float* Phi_e     = (const float*)d_in[5];
    const float* fe_points = (const float*)d_in[6];
    const int*   n_p       = (const int*)d_in[7];
    float* out = (float*)d_out;

    const int blocks = BATCH / NROW;   // 8192
    sav_kernel<<<blocks, NT, 0, stream>>>(y0, dp, dm, omega_sq, mu, Phi_e,
                                          fe_points, n_p, out);
}

// Round 8
// 46.201 us; speedup vs baseline: 1.0255x; 1.0255x over previous
//
#include <hip/hip_runtime.h>

#define BATCH 262144
#define M 64
#define NROW 32              // 32*516B = 16512B = 129*128B -> block region 128B-aligned
#define ROWDW 129            // dwords per row
#define NDW (NROW * ROWDW)   // 4128 dwords per block region
#define NV4 (NDW / 4)        // 1032 float4 = 4*256 + 8
#define NT 256

constexpr float KDT  = 1.0f / 48000.0f;
constexpr float EPSF = 1e-12f;

typedef float f4 __attribute__((ext_vector_type(4)));

// DPP rotation-add within a 16-lane row group: after ror 1,2,4,8 every lane
// holds the full 16-lane sum. Pure VALU, no LDS pipe.
template <int CTRL>
__device__ __forceinline__ float dpp_ror_add(float x) {
    int xi = __builtin_bit_cast(int, x);
    int r  = __builtin_amdgcn_update_dpp(0, xi, CTRL, 0xF, 0xF, true);
    return x + __builtin_bit_cast(float, r);
}
__device__ __forceinline__ float rsum16(float x) {
    x = dpp_ror_add<0x121>(x);  // row_ror:1
    x = dpp_ror_add<0x122>(x);  // row_ror:2
    x = dpp_ror_add<0x124>(x);  // row_ror:4
    x = dpp_ror_add<0x128>(x);  // row_ror:8
    return x;
}

__global__ __launch_bounds__(NT) void sav_kernel(
    const float* __restrict__ y0,
    const float* __restrict__ dp,
    const float* __restrict__ dm,
    const float* __restrict__ omega_sq,
    const float* __restrict__ mu_p,
    const float* __restrict__ Phi_e,
    const float* __restrict__ fe_points,
    const int*   __restrict__ n_p,
    float* __restrict__ out)
{
    // LDS mirrors global layout (stride 129 dwords). 129 % 32 == 1 keeps
    // compute-phase scalar reads 2-way bank aliased (free per m136).
    __shared__ float lds[NDW];   // 16512 B -> 8 blocks/CU fits in 160KB
    f4* lds4 = (f4*)lds;

    const int tid = threadIdx.x;

    // ---------- load phase: issue all global loads first ----------
    const f4* gin = (const f4*)(y0 + (size_t)blockIdx.x * NDW);
    const f4 v0 = gin[tid];
    const f4 v1 = gin[tid + NT];
    const f4 v2 = gin[tid + 2 * NT];
    const f4 v3 = gin[tid + 3 * NT];
    f4 vt = {};
    if (tid < NV4 - 4 * NT) vt = gin[tid + 4 * NT];

    const int lane = tid & 63;
    const int sl   = lane & 15;       // sub-lane within 16-lane group
    const int g    = tid >> 4;        // group 0..15; handles rows g and g+16

    const int   n  = *n_p;
    const float mu = *mu_p;

    const f4 dpv = ((const f4*)dp)[sl];
    const f4 dmv = ((const f4*)dm)[sl];
    const f4 osq = ((const f4*)omega_sq)[sl];
    const f4 phe = ((const f4*)Phi_e)[sl];

    const int bA = blockIdx.x * NROW + g;   // row for pass 0
    const float feA = fe_points[(size_t)bA * 16 + n];
    const float feB = fe_points[(size_t)(bA + 16) * 16 + n];

    lds4[tid]          = v0;
    lds4[tid + NT]     = v1;
    lds4[tid + 2 * NT] = v2;
    lds4[tid + 3 * NT] = v3;
    if (tid < NV4 - 4 * NT) lds4[tid + 4 * NT] = vt;

    __syncthreads();

    // ---------- compute phase: 2 rows per group, sequential ----------
    const float c   = 0.5f * KDT * mu;
    const float mu2 = mu * mu;
    float idp[4];
    #pragma unroll
    for (int j = 0; j < 4; ++j) idp[j] = __builtin_amdgcn_rcpf(dpv[j]);

    #pragma unroll 1
    for (int rr = 0; rr < 2; ++rr) {
        const int r = g + 16 * rr;          // rows g, g+16: keeps banks 2-way
        const float fe = rr ? feB : feA;
        float* lrow = &lds[r * ROWDW];

        float q0v[4], p0v[4];
        #pragma unroll
        for (int j = 0; j < 4; ++j) {
            q0v[j] = lrow[4 * sl + j];
            p0v[j] = lrow[M + 4 * sl + j];
        }
        const float psi0 = lrow[2 * M];

        float qh[4], q3[4];
        float lq4 = 0.0f;
        #pragma unroll
        for (int j = 0; j < 4; ++j) {
            const float q  = q0v[j] + 0.5f * KDT * p0v[j];
            const float q2 = q * q;
            qh[j] = q;
            q3[j] = q2 * q;
            lq4  += q2 * q2;
        }

        const float s = rsum16(lq4);                      // sum(qh^4)
        const float inv_psi = __builtin_amdgcn_rsqf(0.5f * s + EPSF);

        float g0[4], b0[4];
        float ls1 = 0.0f, ls3 = 0.0f;
        #pragma unroll
        for (int j = 0; j < 4; ++j) {
            g0[j] = -q3[j] * inv_psi;
            const float a0 = c * g0[j];
            b0[j] = a0 * idp[j];
            ls1 += a0 * p0v[j];
            ls3 += a0 * b0[j];
        }

        const float s1 = rsum16(ls1);                     // sum(a0*p0)
        const float s3 = rsum16(ls3);                     // sum(a0*b0)

        // p1 pre-division (reference uses THIS value inside sum(b0*p1))
        const float mu2psi = mu2 * psi0;
        float p1p[4];
        float ls2 = 0.0f;
        #pragma unroll
        for (int j = 0; j < 4; ++j) {
            p1p[j] = dmv[j] * p0v[j] - (c * g0[j]) * s1
                   + KDT * (-osq[j] * qh[j] - mu2psi * g0[j] + phe[j] * fe);
            ls2 += b0[j] * p1p[j];
        }

        const float s2 = rsum16(ls2);                     // sum(b0*p1_pre)
        const float t  = s2 * __builtin_amdgcn_rcpf(1.0f + s3);

        float p1[4];
        float lsg = 0.0f;
        #pragma unroll
        for (int j = 0; j < 4; ++j) {
            p1[j] = p1p[j] * idp[j] - b0[j] * t;
            lsg  += g0[j] * (0.5f * (p0v[j] + p1[j]));
        }

        const float sg   = rsum16(lsg);                   // sum(g0*p_half)
        const float psi1 = psi0 + KDT * sg;

        // write back to the same LDS cells (rows disjoint across groups/passes)
        #pragma unroll
        for (int j = 0; j < 4; ++j) {
            lrow[4 * sl + j]     = qh[j] + 0.5f * KDT * p1[j];  // q1
            lrow[M + 4 * sl + j] = p1[j];
        }
        if (sl == 0) lrow[2 * M] = psi1;
    }

    __syncthreads();

    // ---------- store phase: contiguous, 128B-aligned, nontemporal ----------
    f4* gout = (f4*)(out + (size_t)blockIdx.x * NDW);
    __builtin_nontemporal_store(lds4[tid],          &gout[tid]);
    __builtin_nontemporal_store(lds4[tid + NT],     &gout[tid + NT]);
    __builtin_nontemporal_store(lds4[tid + 2 * NT], &gout[tid + 2 * NT]);
    __builtin_nontemporal_store(lds4[tid + 3 * NT], &gout[tid + 3 * NT]);
    if (tid < NV4 - 4 * NT)
        __builtin_nontemporal_store(lds4[tid + 4 * NT], &gout[tid + 4 * NT]);
}

extern "C" void kernel_launch(void* const* d_in, const int* in_sizes, int n_in,
                              void* d_out, int out_size, void* d_ws, size_t ws_size,
                              hipStream_t stream) {
    const float* y0        = (const float*)d_in[0];
    const float* dp        = (const float*)d_in[1];
    const float* dm        = (const float*)d_in[2];
    const float* omega_sq  = (const float*)d_in[3];
    const float* mu        = (const float*)d_in[4];
    const float* Phi_e     = (const float*)d_in[5];
    const float* fe_points = (const float*)d_in[6];
    const int*   n_p       = (const int*)d_in[7];
    float* out = (float*)d_out;

    const int blocks = BATCH / NROW;   // 8192
    sav_kernel<<<blocks, NT, 0, stream>>>(y0, dp, dm, omega_sq, mu, Phi_e,
                                          fe_points, n_p, out);
}